// Round 1
// baseline (4128.835 us; speedup 1.0000x reference)
//
#include <hip/hip_runtime.h>
#include <math.h>

#define D_MODEL 1024
#define N_HEADS 16
#define D_K     64
#define S_LEN   2048
#define B_SZ    2

// ---------------------------------------------------------------------------
// GEMM: C[M][N] = A[M][K] * B[N][K]^T   (row-major, K contiguous in both)
// Matches einsum 'bsi,oi->bso'. 64x64 block tile, 256 threads, 4x4 per thread.
// ---------------------------------------------------------------------------
#define BM 64
#define BN 64
#define BK 16

__global__ __launch_bounds__(256)
void gemm_nt(const float* __restrict__ A, const float* __restrict__ Bm,
             float* __restrict__ C, int M, int N, int K) {
    __shared__ float As[BK][BM + 1];
    __shared__ float Bs[BK][BN + 1];
    const int tid = threadIdx.x;            // 0..255
    const int tx = tid & 15;                // col group
    const int ty = tid >> 4;                // row group
    const int row0 = blockIdx.y * BM;
    const int col0 = blockIdx.x * BN;

    float acc[4][4] = {};

    for (int k0 = 0; k0 < K; k0 += BK) {
        // Load A tile (BM x BK = 1024 elems, 4 per thread), store transposed
#pragma unroll
        for (int i = 0; i < 4; i++) {
            int e  = tid + i * 256;
            int m  = e >> 4;
            int kk = e & 15;
            As[kk][m] = A[(size_t)(row0 + m) * K + (k0 + kk)];
        }
#pragma unroll
        for (int i = 0; i < 4; i++) {
            int e  = tid + i * 256;
            int n  = e >> 4;
            int kk = e & 15;
            Bs[kk][n] = Bm[(size_t)(col0 + n) * K + (k0 + kk)];
        }
        __syncthreads();

#pragma unroll
        for (int kk = 0; kk < BK; kk++) {
            float a[4], b[4];
#pragma unroll
            for (int i = 0; i < 4; i++) a[i] = As[kk][ty * 4 + i];
#pragma unroll
            for (int j = 0; j < 4; j++) b[j] = Bs[kk][tx * 4 + j];
#pragma unroll
            for (int i = 0; i < 4; i++)
#pragma unroll
                for (int j = 0; j < 4; j++)
                    acc[i][j] += a[i] * b[j];
        }
        __syncthreads();
    }

#pragma unroll
    for (int i = 0; i < 4; i++) {
        int m = row0 + ty * 4 + i;
#pragma unroll
        for (int j = 0; j < 4; j++) {
            int n = col0 + tx * 4 + j;
            C[(size_t)m * N + n] = acc[i][j];
        }
    }
}

// ---------------------------------------------------------------------------
// RoPE applied in place to the Q (w=0) and K (w=1) slices of qkv.
// qkv layout: (B, S, 3, H, D_K) flat. One thread per (b,s,w,h,freq j).
// ---------------------------------------------------------------------------
__global__ __launch_bounds__(256)
void rope_kernel(float* __restrict__ qkv, const int* __restrict__ pos) {
    int idx = blockIdx.x * blockDim.x + threadIdx.x;
    // bits: j:5, h:4, w:1, s:11, b:1  -> total 2*2048*2*16*32 = 4,194,304
    int j = idx & 31;
    int h = (idx >> 5) & 15;
    int w = (idx >> 9) & 1;
    int s = (idx >> 10) & 2047;
    int b = idx >> 21;

    float p = (float)pos[s];
    // inv_freq = 10000^(-2j/64)
    float inv_freq = __powf(10000.0f, -(float)(2 * j) / 64.0f);
    float ang = p * inv_freq;
    float sn, cs;
    sincosf(ang, &sn, &cs);

    size_t base = (((size_t)(b * S_LEN + s) * 3 + w) * D_MODEL) + h * D_K + 2 * j;
    float x1 = qkv[base];
    float x2 = qkv[base + 1];
    qkv[base]     = x1 * cs - x2 * sn;
    qkv[base + 1] = x1 * sn + x2 * cs;
}

// ---------------------------------------------------------------------------
// Attention: one block (256 thr) per (b, h, q). Two-pass softmax with scores
// staged in LDS, then V accumulation split 4-ways over k, reduced in LDS.
// Writes output directly in (B, S, H*D_K) layout for the final projection.
// ---------------------------------------------------------------------------
__global__ __launch_bounds__(256)
void attn_kernel(const float* __restrict__ qkv, float* __restrict__ out) {
    const int q   = blockIdx.x;
    const int h   = blockIdx.y;
    const int b   = blockIdx.z;
    const int tid = threadIdx.x;

    __shared__ float qs[D_K];
    __shared__ float p[S_LEN];
    __shared__ float red[4][D_K];
    __shared__ float wred[4];
    __shared__ float m_sh, l_sh;

    const float* Q = qkv + ((size_t)(b * S_LEN + q) * 3 + 0) * D_MODEL + h * D_K;
    if (tid < D_K) qs[tid] = Q[tid] * 0.125f;   // 1/sqrt(64)
    __syncthreads();

    const int len = q + 1;   // causal: keys 0..q inclusive

    // ---- pass 1: raw scores + running max ----
    float lmax = -INFINITY;
    for (int k = tid; k < len; k += 256) {
        const float* Kr = qkv + ((size_t)(b * S_LEN + k) * 3 + 1) * D_MODEL + h * D_K;
        float s = 0.f;
#pragma unroll
        for (int d = 0; d < D_K; d++) s += qs[d] * Kr[d];
        p[k] = s;
        lmax = fmaxf(lmax, s);
    }
#pragma unroll
    for (int off = 32; off > 0; off >>= 1)
        lmax = fmaxf(lmax, __shfl_down(lmax, off, 64));
    if ((tid & 63) == 0) wred[tid >> 6] = lmax;
    __syncthreads();
    if (tid == 0)
        m_sh = fmaxf(fmaxf(wred[0], wred[1]), fmaxf(wred[2], wred[3]));
    __syncthreads();
    const float m = m_sh;

    // ---- pass 2: exponentiate + sum ----
    float lsum = 0.f;
    for (int k = tid; k < len; k += 256) {
        float e = __expf(p[k] - m);
        p[k] = e;
        lsum += e;
    }
#pragma unroll
    for (int off = 32; off > 0; off >>= 1)
        lsum += __shfl_down(lsum, off, 64);
    if ((tid & 63) == 0) wred[tid >> 6] = lsum;
    __syncthreads();
    if (tid == 0) l_sh = wred[0] + wred[1] + wred[2] + wred[3];
    __syncthreads();
    const float inv_l = 1.0f / l_sh;

    // ---- pass 3: o[d] = sum_k p[k] * V[k][d] ----
    const int d = tid & 63;
    const int g = tid >> 6;
    float acc = 0.f;
    for (int k = g; k < len; k += 4) {
        const float* Vr = qkv + ((size_t)(b * S_LEN + k) * 3 + 2) * D_MODEL + h * D_K;
        acc += p[k] * Vr[d];
    }
    red[g][d] = acc;
    __syncthreads();
    if (tid < D_K) {
        float o = (red[0][tid] + red[1][tid] + red[2][tid] + red[3][tid]) * inv_l;
        out[(size_t)(b * S_LEN + q) * D_MODEL + h * D_K + tid] = o;
    }
}

// ---------------------------------------------------------------------------
extern "C" void kernel_launch(void* const* d_in, const int* in_sizes, int n_in,
                              void* d_out, int out_size, void* d_ws, size_t ws_size,
                              hipStream_t stream) {
    const float* x    = (const float*)d_in[0];   // (B, S, D_MODEL)
    const int*   pos  = (const int*)d_in[1];     // (S,)
    const float* Wqkv = (const float*)d_in[2];   // (3*D_MODEL, D_MODEL)
    const float* Wout = (const float*)d_in[3];   // (D_MODEL, D_MODEL)
    float*       out  = (float*)d_out;           // (B, S, D_MODEL)

    float* qkv = (float*)d_ws;                                   // B*S*3*D_MODEL fp32 = 50.3 MB
    float* ao  = qkv + (size_t)B_SZ * S_LEN * 3 * D_MODEL;       // B*S*D_MODEL fp32 = 16.8 MB

    const int M = B_SZ * S_LEN;      // 4096

    // 1) qkv = x @ W_qkv^T
    gemm_nt<<<dim3(3 * D_MODEL / BN, M / BM), 256, 0, stream>>>(
        x, Wqkv, qkv, M, 3 * D_MODEL, D_MODEL);

    // 2) RoPE in place on Q and K slices
    rope_kernel<<<(B_SZ * S_LEN * 2 * N_HEADS * 32) / 256, 256, 0, stream>>>(qkv, pos);

    // 3) causal attention -> ao in (B, S, H*D_K) layout
    attn_kernel<<<dim3(S_LEN, N_HEADS, B_SZ), 256, 0, stream>>>(qkv, ao);

    // 4) out = ao @ W_out^T
    gemm_nt<<<dim3(D_MODEL / BN, M / BM), 256, 0, stream>>>(
        ao, Wout, out, M, D_MODEL, D_MODEL);
}

// Round 2
// 1337.841 us; speedup vs baseline: 3.0862x; 3.0862x over previous
//
#include <hip/hip_runtime.h>
#include <math.h>

#define D_MODEL 1024
#define N_HEADS 16
#define D_K     64
#define S_LEN   2048
#define B_SZ    2

// ---------------------------------------------------------------------------
// GEMM: C[M][N] = A[M][K] * B[N][K]^T   (row-major, K contiguous in both)
// Matches einsum 'bsi,oi->bso'. 64x64 block tile, 256 threads, 4x4 per thread.
// ---------------------------------------------------------------------------
#define BM 64
#define BN 64
#define BK 16

__global__ __launch_bounds__(256)
void gemm_nt(const float* __restrict__ A, const float* __restrict__ Bm,
             float* __restrict__ C, int M, int N, int K) {
    __shared__ float As[BK][BM + 1];
    __shared__ float Bs[BK][BN + 1];
    const int tid = threadIdx.x;            // 0..255
    const int tx = tid & 15;                // col group
    const int ty = tid >> 4;                // row group
    const int row0 = blockIdx.y * BM;
    const int col0 = blockIdx.x * BN;

    float acc[4][4] = {};

    for (int k0 = 0; k0 < K; k0 += BK) {
#pragma unroll
        for (int i = 0; i < 4; i++) {
            int e  = tid + i * 256;
            int m  = e >> 4;
            int kk = e & 15;
            As[kk][m] = A[(size_t)(row0 + m) * K + (k0 + kk)];
        }
#pragma unroll
        for (int i = 0; i < 4; i++) {
            int e  = tid + i * 256;
            int n  = e >> 4;
            int kk = e & 15;
            Bs[kk][n] = Bm[(size_t)(col0 + n) * K + (k0 + kk)];
        }
        __syncthreads();

#pragma unroll
        for (int kk = 0; kk < BK; kk++) {
            float a[4], b[4];
#pragma unroll
            for (int i = 0; i < 4; i++) a[i] = As[kk][ty * 4 + i];
#pragma unroll
            for (int j = 0; j < 4; j++) b[j] = Bs[kk][tx * 4 + j];
#pragma unroll
            for (int i = 0; i < 4; i++)
#pragma unroll
                for (int j = 0; j < 4; j++)
                    acc[i][j] += a[i] * b[j];
        }
        __syncthreads();
    }

#pragma unroll
    for (int i = 0; i < 4; i++) {
        int m = row0 + ty * 4 + i;
#pragma unroll
        for (int j = 0; j < 4; j++) {
            int n = col0 + tx * 4 + j;
            C[(size_t)m * N + n] = acc[i][j];
        }
    }
}

// ---------------------------------------------------------------------------
// RoPE applied in place to the Q (w=0) and K (w=1) slices of qkv.
// qkv layout: (B, S, 3, H, D_K) flat. One thread per (b,s,w,h,freq j).
// ---------------------------------------------------------------------------
__global__ __launch_bounds__(256)
void rope_kernel(float* __restrict__ qkv, const int* __restrict__ pos) {
    int idx = blockIdx.x * blockDim.x + threadIdx.x;
    int j = idx & 31;
    int h = (idx >> 5) & 15;
    int w = (idx >> 9) & 1;
    int s = (idx >> 10) & 2047;
    int b = idx >> 21;

    float p = (float)pos[s];
    float inv_freq = __powf(10000.0f, -(float)(2 * j) / 64.0f);
    float ang = p * inv_freq;
    float sn, cs;
    sincosf(ang, &sn, &cs);

    size_t base = (((size_t)(b * S_LEN + s) * 3 + w) * D_MODEL) + h * D_K + 2 * j;
    float x1 = qkv[base];
    float x2 = qkv[base + 1];
    qkv[base]     = x1 * cs - x2 * sn;
    qkv[base + 1] = x1 * sn + x2 * cs;
}

// ---------------------------------------------------------------------------
// Flash-style tiled causal attention, fp32.
// One block (256 thr) per (b, h, 64-query tile). K/V tiles staged in LDS;
// 4x4 register sub-tile per thread; online softmax; P round-trips via LDS.
// Thread (ty,tx): rows q = 4*ty+i (blocked), cols = tx + 16*j (strided).
// LDS rows padded to 68 floats: 16B-aligned float4 reads, worst conflict 2-way (free).
// ---------------------------------------------------------------------------
#define PAD 68

__global__ __launch_bounds__(256)
void attn_tiled(const float* __restrict__ qkv, float* __restrict__ out) {
    const int qt = gridDim.x - 1 - blockIdx.x;   // longest blocks launch first
    const int h  = blockIdx.y;
    const int b  = blockIdx.z;
    const int tid = threadIdx.x;
    const int tx = tid & 15;
    const int ty = tid >> 4;

    __shared__ float Qs[64][PAD];
    __shared__ float Ks[64][PAD];
    __shared__ float Vs[64][PAD];
    __shared__ float Ps[64][PAD];

    const size_t hoff = (size_t)h * D_K;

    // ---- stage Q tile (scaled by 1/sqrt(d_k)) ----
#pragma unroll
    for (int i = 0; i < 4; i++) {
        int e  = tid + i * 256;       // 0..1023
        int r  = e >> 4;              // row 0..63
        int c4 = e & 15;              // float4 col
        int qg = qt * 64 + r;
        const float4* Qp = (const float4*)(qkv + ((size_t)(b * S_LEN + qg) * 3 + 0) * D_MODEL + hoff);
        float4 v = Qp[c4];
        v.x *= 0.125f; v.y *= 0.125f; v.z *= 0.125f; v.w *= 0.125f;
        *(float4*)&Qs[r][c4 * 4] = v;
    }

    float o[4][4] = {};
    float m[4], l[4];
#pragma unroll
    for (int i = 0; i < 4; i++) { m[i] = -INFINITY; l[i] = 0.f; }

    for (int kt = 0; kt <= qt; kt++) {
        __syncthreads();   // prev iter's LDS reads done (also covers Qs staging)

        // ---- stage K and V tiles ----
#pragma unroll
        for (int i = 0; i < 4; i++) {
            int e  = tid + i * 256;
            int r  = e >> 4;
            int c4 = e & 15;
            int kg = kt * 64 + r;
            const float4* Kp = (const float4*)(qkv + ((size_t)(b * S_LEN + kg) * 3 + 1) * D_MODEL + hoff);
            const float4* Vp = (const float4*)(qkv + ((size_t)(b * S_LEN + kg) * 3 + 2) * D_MODEL + hoff);
            *(float4*)&Ks[r][c4 * 4] = Kp[c4];
            *(float4*)&Vs[r][c4 * 4] = Vp[c4];
        }
        __syncthreads();

        // ---- S tile: s[i][j] = sum_d Qs[4ty+i][d] * Ks[tx+16j][d] ----
        float s[4][4] = {};
        for (int d0 = 0; d0 < 64; d0 += 4) {
            float4 a4[4], b4[4];
#pragma unroll
            for (int i = 0; i < 4; i++) a4[i] = *(const float4*)&Qs[ty * 4 + i][d0];
#pragma unroll
            for (int j = 0; j < 4; j++) b4[j] = *(const float4*)&Ks[tx + 16 * j][d0];
#pragma unroll
            for (int i = 0; i < 4; i++)
#pragma unroll
                for (int j = 0; j < 4; j++)
                    s[i][j] += a4[i].x * b4[j].x + a4[i].y * b4[j].y
                             + a4[i].z * b4[j].z + a4[i].w * b4[j].w;
        }

        // ---- causal mask on the diagonal tile ----
        if (kt == qt) {
#pragma unroll
            for (int i = 0; i < 4; i++) {
                int ql = 4 * ty + i;
#pragma unroll
                for (int j = 0; j < 4; j++) {
                    int kl = tx + 16 * j;
                    if (kl > ql) s[i][j] = -INFINITY;
                }
            }
        }

        // ---- online softmax update + write P ----
#pragma unroll
        for (int i = 0; i < 4; i++) {
            float rmax = fmaxf(fmaxf(s[i][0], s[i][1]), fmaxf(s[i][2], s[i][3]));
#pragma unroll
            for (int off = 1; off < 16; off <<= 1)
                rmax = fmaxf(rmax, __shfl_xor(rmax, off, 64));
            float mn = fmaxf(m[i], rmax);
            float alpha = __expf(m[i] - mn);
            float rsum = 0.f;
#pragma unroll
            for (int j = 0; j < 4; j++) {
                float p = __expf(s[i][j] - mn);
                s[i][j] = p;
                rsum += p;
            }
#pragma unroll
            for (int off = 1; off < 16; off <<= 1)
                rsum += __shfl_xor(rsum, off, 64);
            l[i] = l[i] * alpha + rsum;
            m[i] = mn;
#pragma unroll
            for (int j = 0; j < 4; j++) o[i][j] *= alpha;
#pragma unroll
            for (int j = 0; j < 4; j++) Ps[4 * ty + i][tx + 16 * j] = s[i][j];
        }
        __syncthreads();

        // ---- o += P @ V : o[i][j] += sum_k Ps[4ty+i][k] * Vs[k][tx+16j] ----
        for (int kk = 0; kk < 64; kk++) {
            float a[4], bv[4];
#pragma unroll
            for (int i = 0; i < 4; i++) a[i] = Ps[4 * ty + i][kk];
#pragma unroll
            for (int j = 0; j < 4; j++) bv[j] = Vs[kk][tx + 16 * j];
#pragma unroll
            for (int i = 0; i < 4; i++)
#pragma unroll
                for (int j = 0; j < 4; j++)
                    o[i][j] += a[i] * bv[j];
        }
    }

    // ---- epilogue: normalize and store (B, S, H*D_K) ----
#pragma unroll
    for (int i = 0; i < 4; i++) {
        int qg = qt * 64 + 4 * ty + i;
        float invl = 1.f / l[i];
#pragma unroll
        for (int j = 0; j < 4; j++)
            out[(size_t)(b * S_LEN + qg) * D_MODEL + hoff + tx + 16 * j] = o[i][j] * invl;
    }
}

// ---------------------------------------------------------------------------
extern "C" void kernel_launch(void* const* d_in, const int* in_sizes, int n_in,
                              void* d_out, int out_size, void* d_ws, size_t ws_size,
                              hipStream_t stream) {
    const float* x    = (const float*)d_in[0];   // (B, S, D_MODEL)
    const int*   pos  = (const int*)d_in[1];     // (S,)
    const float* Wqkv = (const float*)d_in[2];   // (3*D_MODEL, D_MODEL)
    const float* Wout = (const float*)d_in[3];   // (D_MODEL, D_MODEL)
    float*       out  = (float*)d_out;           // (B, S, D_MODEL)

    float* qkv = (float*)d_ws;                                   // B*S*3*D_MODEL fp32
    float* ao  = qkv + (size_t)B_SZ * S_LEN * 3 * D_MODEL;       // B*S*D_MODEL fp32

    const int M = B_SZ * S_LEN;      // 4096

    // 1) qkv = x @ W_qkv^T
    gemm_nt<<<dim3(3 * D_MODEL / BN, M / BM), 256, 0, stream>>>(
        x, Wqkv, qkv, M, 3 * D_MODEL, D_MODEL);

    // 2) RoPE in place on Q and K slices
    rope_kernel<<<(B_SZ * S_LEN * 2 * N_HEADS * 32) / 256, 256, 0, stream>>>(qkv, pos);

    // 3) causal attention -> ao in (B, S, H*D_K) layout
    attn_tiled<<<dim3(S_LEN / 64, N_HEADS, B_SZ), 256, 0, stream>>>(qkv, ao);

    // 4) out = ao @ W_out^T
    gemm_nt<<<dim3(D_MODEL / BN, M / BM), 256, 0, stream>>>(
        ao, Wout, out, M, D_MODEL, D_MODEL);
}

// Round 3
// 753.209 us; speedup vs baseline: 5.4817x; 1.7762x over previous
//
#include <hip/hip_runtime.h>
#include <hip/hip_bf16.h>
#include <math.h>

#define D_MODEL 1024
#define N_HEADS 16
#define D_K     64
#define S_LEN   2048
#define B_SZ    2

typedef unsigned short u16;
using short8 = __attribute__((ext_vector_type(8))) short;
using f32x4  = __attribute__((ext_vector_type(4))) float;

__device__ inline float bf2f(u16 u) { return __uint_as_float((unsigned)u << 16); }
__device__ inline u16 f2bf(float f) {
    __hip_bfloat16 h = __float2bfloat16(f);   // RNE
    return *(u16*)&h;
}
__device__ inline void gload_lds16(const void* g, void* l) {
    __builtin_amdgcn_global_load_lds(
        (const __attribute__((address_space(1))) unsigned int*)g,
        (__attribute__((address_space(3))) unsigned int*)l, 16, 0, 0);
}

// ---------------------------------------------------------------------------
// fp32 -> bf16 cast, float4/ushort4 vectorized. n must be divisible by 4.
// ---------------------------------------------------------------------------
__global__ __launch_bounds__(256)
void cast_f32_bf16(const float* __restrict__ in, u16* __restrict__ out, int n4) {
    int i = blockIdx.x * 256 + threadIdx.x;
    if (i >= n4) return;
    float4 v = ((const float4*)in)[i];
    ushort4 u;
    u.x = f2bf(v.x); u.y = f2bf(v.y); u.z = f2bf(v.z); u.w = f2bf(v.w);
    ((ushort4*)out)[i] = u;
}

// ---------------------------------------------------------------------------
// bf16 MFMA GEMM (m97 structure): C[M][N] = A[M][K] * B[N][K]^T.
// A, B bf16 row-major K-contiguous. 128x128 tile, BK=32, 4 waves (2x2),
// each wave 64x64 = 4x4 grid of 16x16x32 MFMA tiles.
// LDS layout [row][32] bf16 contiguous (required by global_load_lds: dest is
// wave-uniform base + lane*16B -> lane i covers row i/4, k-bytes (i%4)*16).
// ---------------------------------------------------------------------------
template <bool OUT_BF16>
__global__ __launch_bounds__(256)
void gemm_bt_mfma(const u16* __restrict__ A, const u16* __restrict__ B,
                  void* __restrict__ Cout, int M, int N, int K) {
    __shared__ u16 As[128 * 32];
    __shared__ u16 Bs[128 * 32];
    const int tid  = threadIdx.x;
    const int lane = tid & 63;
    const int wv   = tid >> 6;
    const int wm   = wv >> 1, wn = wv & 1;
    const int row0 = blockIdx.y * 128;
    const int col0 = blockIdx.x * 128;

    const int lr = lane >> 2;          // row within a 16-row staging chunk
    const int lc = (lane & 3) * 8;     // k-element offset (8 bf16 = 16 B)

    f32x4 acc[4][4] = {};

    for (int k0 = 0; k0 < K; k0 += 32) {
#pragma unroll
        for (int t = 0; t < 2; t++) {
            int rblk = wv * 32 + t * 16;   // wave-uniform
            gload_lds16(A + (size_t)(row0 + rblk + lr) * K + k0 + lc, &As[rblk * 32]);
            gload_lds16(B + (size_t)(col0 + rblk + lr) * K + k0 + lc, &Bs[rblk * 32]);
        }
        __syncthreads();   // drains vmcnt -> LDS tiles complete

        short8 af[4], bfr[4];
#pragma unroll
        for (int mi = 0; mi < 4; mi++)
            af[mi] = *(const short8*)&As[(wm * 64 + mi * 16 + (lane & 15)) * 32 + (lane >> 4) * 8];
#pragma unroll
        for (int nj = 0; nj < 4; nj++)
            bfr[nj] = *(const short8*)&Bs[(wn * 64 + nj * 16 + (lane & 15)) * 32 + (lane >> 4) * 8];
#pragma unroll
        for (int mi = 0; mi < 4; mi++)
#pragma unroll
            for (int nj = 0; nj < 4; nj++)
                acc[mi][nj] = __builtin_amdgcn_mfma_f32_16x16x32_bf16(
                    af[mi], bfr[nj], acc[mi][nj], 0, 0, 0);
        __syncthreads();
    }

    const int cr = (lane >> 4) * 4;   // C/D: row = quad*4 + reg
    const int cc = lane & 15;         //      col = lane & 15
#pragma unroll
    for (int mi = 0; mi < 4; mi++) {
#pragma unroll
        for (int nj = 0; nj < 4; nj++) {
            int c = col0 + wn * 64 + nj * 16 + cc;
#pragma unroll
            for (int r = 0; r < 4; r++) {
                int rr = row0 + wm * 64 + mi * 16 + cr + r;
                if (OUT_BF16)
                    ((u16*)Cout)[(size_t)rr * N + c] = f2bf(acc[mi][nj][r]);
                else
                    ((float*)Cout)[(size_t)rr * N + c] = acc[mi][nj][r];
            }
        }
    }
}

// ---------------------------------------------------------------------------
// RoPE in place on bf16 qkv (Q and K slices). One thread per (b,s,w,h,j).
// ---------------------------------------------------------------------------
__global__ __launch_bounds__(256)
void rope_bf16(u16* __restrict__ qkv, const int* __restrict__ pos) {
    int idx = blockIdx.x * blockDim.x + threadIdx.x;
    int j = idx & 31;
    int h = (idx >> 5) & 15;
    int w = (idx >> 9) & 1;
    int s = (idx >> 10) & 2047;
    int b = idx >> 21;

    float p = (float)pos[s];
    float inv_freq = __powf(10000.0f, -(float)(2 * j) / 64.0f);
    float ang = p * inv_freq;
    float sn, cs;
    sincosf(ang, &sn, &cs);

    size_t base = (((size_t)(b * S_LEN + s) * 3 + w) * D_MODEL) + h * D_K + 2 * j;
    float x1 = bf2f(qkv[base]);
    float x2 = bf2f(qkv[base + 1]);
    qkv[base]     = f2bf(x1 * cs - x2 * sn);
    qkv[base + 1] = f2bf(x1 * sn + x2 * cs);
}

// ---------------------------------------------------------------------------
// Flash-style tiled causal attention. bf16 in (qkv), fp32 compute, bf16 out.
// Structure identical to round 1 (64x64 tiles, 4x4 reg sub-tile, online
// softmax); only the global<->LDS dtype changed.
// ---------------------------------------------------------------------------
#define PAD 68

__global__ __launch_bounds__(256)
void attn_tiled(const u16* __restrict__ qkv, u16* __restrict__ out) {
    const int qt = gridDim.x - 1 - blockIdx.x;   // longest blocks first
    const int h  = blockIdx.y;
    const int b  = blockIdx.z;
    const int tid = threadIdx.x;
    const int tx = tid & 15;
    const int ty = tid >> 4;

    __shared__ float Qs[64][PAD];
    __shared__ float Ks[64][PAD];
    __shared__ float Vs[64][PAD];
    __shared__ float Ps[64][PAD];

    const size_t hoff = (size_t)h * D_K;

    // ---- stage Q tile (scaled by 1/sqrt(d_k)) ----
#pragma unroll
    for (int i = 0; i < 4; i++) {
        int e  = tid + i * 256;
        int r  = e >> 4;
        int c4 = e & 15;
        int qg = qt * 64 + r;
        const u16* Qp = qkv + ((size_t)(b * S_LEN + qg) * 3 + 0) * D_MODEL + hoff;
        ushort4 u = ((const ushort4*)Qp)[c4];
        float4 v;
        v.x = bf2f(u.x) * 0.125f; v.y = bf2f(u.y) * 0.125f;
        v.z = bf2f(u.z) * 0.125f; v.w = bf2f(u.w) * 0.125f;
        *(float4*)&Qs[r][c4 * 4] = v;
    }

    float o[4][4] = {};
    float m[4], l[4];
#pragma unroll
    for (int i = 0; i < 4; i++) { m[i] = -INFINITY; l[i] = 0.f; }

    for (int kt = 0; kt <= qt; kt++) {
        __syncthreads();

#pragma unroll
        for (int i = 0; i < 4; i++) {
            int e  = tid + i * 256;
            int r  = e >> 4;
            int c4 = e & 15;
            int kg = kt * 64 + r;
            const u16* Kp = qkv + ((size_t)(b * S_LEN + kg) * 3 + 1) * D_MODEL + hoff;
            const u16* Vp = qkv + ((size_t)(b * S_LEN + kg) * 3 + 2) * D_MODEL + hoff;
            ushort4 uk = ((const ushort4*)Kp)[c4];
            ushort4 uv = ((const ushort4*)Vp)[c4];
            float4 vk, vv;
            vk.x = bf2f(uk.x); vk.y = bf2f(uk.y); vk.z = bf2f(uk.z); vk.w = bf2f(uk.w);
            vv.x = bf2f(uv.x); vv.y = bf2f(uv.y); vv.z = bf2f(uv.z); vv.w = bf2f(uv.w);
            *(float4*)&Ks[r][c4 * 4] = vk;
            *(float4*)&Vs[r][c4 * 4] = vv;
        }
        __syncthreads();

        float s[4][4] = {};
        for (int d0 = 0; d0 < 64; d0 += 4) {
            float4 a4[4], b4[4];
#pragma unroll
            for (int i = 0; i < 4; i++) a4[i] = *(const float4*)&Qs[ty * 4 + i][d0];
#pragma unroll
            for (int j = 0; j < 4; j++) b4[j] = *(const float4*)&Ks[tx + 16 * j][d0];
#pragma unroll
            for (int i = 0; i < 4; i++)
#pragma unroll
                for (int j = 0; j < 4; j++)
                    s[i][j] += a4[i].x * b4[j].x + a4[i].y * b4[j].y
                             + a4[i].z * b4[j].z + a4[i].w * b4[j].w;
        }

        if (kt == qt) {
#pragma unroll
            for (int i = 0; i < 4; i++) {
                int ql = 4 * ty + i;
#pragma unroll
                for (int j = 0; j < 4; j++) {
                    int kl = tx + 16 * j;
                    if (kl > ql) s[i][j] = -INFINITY;
                }
            }
        }

#pragma unroll
        for (int i = 0; i < 4; i++) {
            float rmax = fmaxf(fmaxf(s[i][0], s[i][1]), fmaxf(s[i][2], s[i][3]));
#pragma unroll
            for (int off = 1; off < 16; off <<= 1)
                rmax = fmaxf(rmax, __shfl_xor(rmax, off, 64));
            float mn = fmaxf(m[i], rmax);
            float alpha = __expf(m[i] - mn);
            float rsum = 0.f;
#pragma unroll
            for (int j = 0; j < 4; j++) {
                float p = __expf(s[i][j] - mn);
                s[i][j] = p;
                rsum += p;
            }
#pragma unroll
            for (int off = 1; off < 16; off <<= 1)
                rsum += __shfl_xor(rsum, off, 64);
            l[i] = l[i] * alpha + rsum;
            m[i] = mn;
#pragma unroll
            for (int j = 0; j < 4; j++) o[i][j] *= alpha;
#pragma unroll
            for (int j = 0; j < 4; j++) Ps[4 * ty + i][tx + 16 * j] = s[i][j];
        }
        __syncthreads();

        for (int kk = 0; kk < 64; kk++) {
            float a[4], bv[4];
#pragma unroll
            for (int i = 0; i < 4; i++) a[i] = Ps[4 * ty + i][kk];
#pragma unroll
            for (int j = 0; j < 4; j++) bv[j] = Vs[kk][tx + 16 * j];
#pragma unroll
            for (int i = 0; i < 4; i++)
#pragma unroll
                for (int j = 0; j < 4; j++)
                    o[i][j] += a[i] * bv[j];
        }
    }

#pragma unroll
    for (int i = 0; i < 4; i++) {
        int qg = qt * 64 + 4 * ty + i;
        float invl = 1.f / l[i];
#pragma unroll
        for (int j = 0; j < 4; j++)
            out[(size_t)(b * S_LEN + qg) * D_MODEL + hoff + tx + 16 * j] =
                f2bf(o[i][j] * invl);
    }
}

// ---------------------------------------------------------------------------
extern "C" void kernel_launch(void* const* d_in, const int* in_sizes, int n_in,
                              void* d_out, int out_size, void* d_ws, size_t ws_size,
                              hipStream_t stream) {
    const float* x    = (const float*)d_in[0];   // (B, S, D_MODEL)
    const int*   pos  = (const int*)d_in[1];     // (S,)
    const float* Wqkv = (const float*)d_in[2];   // (3*D_MODEL, D_MODEL)
    const float* Wout = (const float*)d_in[3];   // (D_MODEL, D_MODEL)
    float*       out  = (float*)d_out;           // (B, S, D_MODEL) fp32

    const int M = B_SZ * S_LEN;                  // 4096

    // workspace (bf16 everywhere): 50.4 MB total
    u16* qkvb = (u16*)d_ws;                          // 4096 x 3072
    u16* aob  = qkvb + (size_t)M * 3 * D_MODEL;      // 4096 x 1024
    u16* xb   = aob  + (size_t)M * D_MODEL;          // 4096 x 1024
    u16* wqb  = xb   + (size_t)M * D_MODEL;          // 3072 x 1024
    u16* wob  = wqb  + (size_t)3 * D_MODEL * D_MODEL;// 1024 x 1024

    // 0) casts to bf16
    cast_f32_bf16<<<(M * D_MODEL / 4 + 255) / 256, 256, 0, stream>>>(x, xb, M * D_MODEL / 4);
    cast_f32_bf16<<<(3 * D_MODEL * D_MODEL / 4 + 255) / 256, 256, 0, stream>>>(Wqkv, wqb, 3 * D_MODEL * D_MODEL / 4);
    cast_f32_bf16<<<(D_MODEL * D_MODEL / 4 + 255) / 256, 256, 0, stream>>>(Wout, wob, D_MODEL * D_MODEL / 4);

    // 1) qkv = x @ W_qkv^T   (bf16 MFMA, bf16 out)
    gemm_bt_mfma<true><<<dim3(3 * D_MODEL / 128, M / 128), 256, 0, stream>>>(
        xb, wqb, qkvb, M, 3 * D_MODEL, D_MODEL);

    // 2) RoPE in place on Q and K slices
    rope_bf16<<<(B_SZ * S_LEN * 2 * N_HEADS * 32) / 256, 256, 0, stream>>>(qkvb, pos);

    // 3) causal attention -> aob (B, S, H*D_K) bf16
    attn_tiled<<<dim3(S_LEN / 64, N_HEADS, B_SZ), 256, 0, stream>>>(qkvb, aob);

    // 4) out = ao @ W_out^T  (bf16 MFMA, fp32 out)
    gemm_bt_mfma<false><<<dim3(D_MODEL / 128, M / 128), 256, 0, stream>>>(
        aob, wob, out, M, D_MODEL, D_MODEL);
}

// Round 4
// 281.741 us; speedup vs baseline: 14.6547x; 2.6734x over previous
//
#include <hip/hip_runtime.h>
#include <hip/hip_bf16.h>
#include <math.h>

#define D_MODEL 1024
#define N_HEADS 16
#define D_K     64
#define S_LEN   2048
#define B_SZ    2

typedef unsigned short u16;
using short8 = __attribute__((ext_vector_type(8))) short;
using f32x4  = __attribute__((ext_vector_type(4))) float;

__device__ inline float bf2f(u16 u) { return __uint_as_float((unsigned)u << 16); }
__device__ inline u16 f2bf(float f) {
    __hip_bfloat16 h = __float2bfloat16(f);   // RNE
    return *(u16*)&h;
}
__device__ inline void gload_lds16(const void* g, void* l) {
    __builtin_amdgcn_global_load_lds(
        (const __attribute__((address_space(1))) unsigned int*)g,
        (__attribute__((address_space(3))) unsigned int*)l, 16, 0, 0);
}

// ---------------------------------------------------------------------------
// fp32 -> bf16 cast, float4/ushort4 vectorized.
// ---------------------------------------------------------------------------
__global__ __launch_bounds__(256)
void cast_f32_bf16(const float* __restrict__ in, u16* __restrict__ out, int n4) {
    int i = blockIdx.x * 256 + threadIdx.x;
    if (i >= n4) return;
    float4 v = ((const float4*)in)[i];
    ushort4 u;
    u.x = f2bf(v.x); u.y = f2bf(v.y); u.z = f2bf(v.z); u.w = f2bf(v.w);
    ((ushort4*)out)[i] = u;
}

// ---------------------------------------------------------------------------
// bf16 MFMA GEMM (m97 structure): C[M][N] = A[M][K] * B[N][K]^T.  (verified R2)
// ---------------------------------------------------------------------------
template <bool OUT_BF16>
__global__ __launch_bounds__(256)
void gemm_bt_mfma(const u16* __restrict__ A, const u16* __restrict__ B,
                  void* __restrict__ Cout, int M, int N, int K) {
    __shared__ u16 As[128 * 32];
    __shared__ u16 Bs[128 * 32];
    const int tid  = threadIdx.x;
    const int lane = tid & 63;
    const int wv   = tid >> 6;
    const int wm   = wv >> 1, wn = wv & 1;
    const int row0 = blockIdx.y * 128;
    const int col0 = blockIdx.x * 128;

    const int lr = lane >> 2;
    const int lc = (lane & 3) * 8;

    f32x4 acc[4][4] = {};

    for (int k0 = 0; k0 < K; k0 += 32) {
#pragma unroll
        for (int t = 0; t < 2; t++) {
            int rblk = wv * 32 + t * 16;
            gload_lds16(A + (size_t)(row0 + rblk + lr) * K + k0 + lc, &As[rblk * 32]);
            gload_lds16(B + (size_t)(col0 + rblk + lr) * K + k0 + lc, &Bs[rblk * 32]);
        }
        __syncthreads();

        short8 af[4], bfr[4];
#pragma unroll
        for (int mi = 0; mi < 4; mi++)
            af[mi] = *(const short8*)&As[(wm * 64 + mi * 16 + (lane & 15)) * 32 + (lane >> 4) * 8];
#pragma unroll
        for (int nj = 0; nj < 4; nj++)
            bfr[nj] = *(const short8*)&Bs[(wn * 64 + nj * 16 + (lane & 15)) * 32 + (lane >> 4) * 8];
#pragma unroll
        for (int mi = 0; mi < 4; mi++)
#pragma unroll
            for (int nj = 0; nj < 4; nj++)
                acc[mi][nj] = __builtin_amdgcn_mfma_f32_16x16x32_bf16(
                    af[mi], bfr[nj], acc[mi][nj], 0, 0, 0);
        __syncthreads();
    }

    const int cr = (lane >> 4) * 4;
    const int cc = lane & 15;
#pragma unroll
    for (int mi = 0; mi < 4; mi++) {
#pragma unroll
        for (int nj = 0; nj < 4; nj++) {
            int c = col0 + wn * 64 + nj * 16 + cc;
#pragma unroll
            for (int r = 0; r < 4; r++) {
                int rr = row0 + wm * 64 + mi * 16 + cr + r;
                if (OUT_BF16)
                    ((u16*)Cout)[(size_t)rr * N + c] = f2bf(acc[mi][nj][r]);
                else
                    ((float*)Cout)[(size_t)rr * N + c] = acc[mi][nj][r];
            }
        }
    }
}

// ---------------------------------------------------------------------------
// RoPE in place on bf16 qkv (Q and K slices); Q additionally scaled by
// 1/sqrt(d_k) so attention scores need no scale.
// ---------------------------------------------------------------------------
__global__ __launch_bounds__(256)
void rope_bf16(u16* __restrict__ qkv, const int* __restrict__ pos) {
    int idx = blockIdx.x * blockDim.x + threadIdx.x;
    int j = idx & 31;
    int h = (idx >> 5) & 15;
    int w = (idx >> 9) & 1;
    int s = (idx >> 10) & 2047;
    int b = idx >> 21;

    float p = (float)pos[s];
    float inv_freq = __powf(10000.0f, -(float)(2 * j) / 64.0f);
    float ang = p * inv_freq;
    float sn, cs;
    sincosf(ang, &sn, &cs);
    float sc = (w == 0) ? 0.125f : 1.0f;

    size_t base = (((size_t)(b * S_LEN + s) * 3 + w) * D_MODEL) + h * D_K + 2 * j;
    float x1 = bf2f(qkv[base]);
    float x2 = bf2f(qkv[base + 1]);
    qkv[base]     = f2bf((x1 * cs - x2 * sn) * sc);
    qkv[base + 1] = f2bf((x1 * sn + x2 * cs) * sc);
}

// ---------------------------------------------------------------------------
// V transpose: qkv V slice (B,S,3,H,D) -> VT (B,H,D,S). 64x64 LDS tile.
// ---------------------------------------------------------------------------
__global__ __launch_bounds__(256)
void vtrans(const u16* __restrict__ qkv, u16* __restrict__ VT) {
    __shared__ u16 t[64][68];   // pad 68: ushort4 stays 8B-aligned (136B rows)
    const int st = blockIdx.x, h = blockIdx.y, b = blockIdx.z;
    const int tid = threadIdx.x;
    const int bh = b * N_HEADS + h;

#pragma unroll
    for (int i = 0; i < 4; i++) {
        int e  = tid + i * 256;
        int sl = e >> 4;
        int c4 = e & 15;
        ushort4 v = *(const ushort4*)&qkv[((size_t)(b * S_LEN + st * 64 + sl) * 3 + 2) * D_MODEL
                                          + h * D_K + c4 * 4];
        *(ushort4*)&t[sl][c4 * 4] = v;
    }
    __syncthreads();
#pragma unroll
    for (int i = 0; i < 4; i++) {
        int e  = tid + i * 256;
        int d  = e >> 4;
        int s4 = e & 15;
        ushort4 o;
        o.x = t[s4 * 4 + 0][d];
        o.y = t[s4 * 4 + 1][d];
        o.z = t[s4 * 4 + 2][d];
        o.w = t[s4 * 4 + 3][d];
        *(ushort4*)&VT[((size_t)bh * D_K + d) * S_LEN + st * 64 + s4 * 4] = o;
    }
}

// ---------------------------------------------------------------------------
// MFMA flash attention (causal). Block = 4 waves per (b, h, 128-q-tile);
// wave w owns rows w*32..w*32+31 (2 m-tiles). K-tile = 64 keys.
// Fragment conventions identical to gemm_bt_mfma (verified):
//   A/B frag: [idx=lane&15][k = quad*8 + j];  C/D: row=quad*4+reg, col=lane&15.
// LDS tiles in m97 [row][32] layout; staged via global_load_lds width 16.
// P (bf16) round-trips LDS; each wave touches only its own P rows -> no barrier.
// ---------------------------------------------------------------------------
__global__ __launch_bounds__(256)
void attn_mfma(const u16* __restrict__ qkv, const u16* __restrict__ VT,
               u16* __restrict__ out) {
    __shared__ u16 Ks[2][64 * 32];    // [d-chunk][key*32 + dL]
    __shared__ u16 VsT[2][64 * 32];   // [key-chunk][d*32 + kL]
    __shared__ u16 Ps[2][128 * 32];   // [key-chunk][row*32 + kL]

    const int tid  = threadIdx.x;
    const int lane = tid & 63;
    const int wv   = tid >> 6;
    const int qt   = gridDim.x - 1 - blockIdx.x;   // longest blocks first
    const int h    = blockIdx.y, b = blockIdx.z;
    const int bh   = b * N_HEADS + h;
    const int q0   = qt * 128;
    const int l15  = lane & 15;
    const int quad = lane >> 4;

    const size_t vtb = (size_t)bh * D_K * S_LEN;

    // Q fragments (Q pre-scaled by 0.125 in rope_bf16)
    short8 qf[2][2];
#pragma unroll
    for (int mi = 0; mi < 2; mi++)
#pragma unroll
        for (int kf = 0; kf < 2; kf++) {
            int row = q0 + wv * 32 + mi * 16 + l15;
            qf[mi][kf] = *(const short8*)&qkv[((size_t)(b * S_LEN + row) * 3 + 0) * D_MODEL
                                              + h * D_K + kf * 32 + quad * 8];
        }

    f32x4 acc[2][4] = {};
    float mrow[2][4], lrow[2][4];
#pragma unroll
    for (int mi = 0; mi < 2; mi++)
#pragma unroll
        for (int r = 0; r < 4; r++) { mrow[mi][r] = -INFINITY; lrow[mi][r] = 0.f; }

    const int wrow_max = q0 + wv * 32 + 31;
    const int nkt = 2 * qt + 2;

    for (int kt = 0; kt < nkt; kt++) {
        const int k0 = kt * 64;
        __syncthreads();   // prior iter's LDS reads complete
        {
            const int lr = lane >> 2;
            const int lc = (lane & 3) * 8;
#pragma unroll
            for (int kf = 0; kf < 2; kf++) {
                int key = k0 + wv * 16 + lr;
                gload_lds16(qkv + ((size_t)(b * S_LEN + key) * 3 + 1) * D_MODEL
                                + h * D_K + kf * 32 + lc,
                            &Ks[kf][(wv * 16) * 32]);
            }
#pragma unroll
            for (int kc = 0; kc < 2; kc++) {
                int d = wv * 16 + lr;
                gload_lds16(VT + vtb + (size_t)d * S_LEN + k0 + kc * 32 + lc,
                            &VsT[kc][(wv * 16) * 32]);
            }
        }
        __syncthreads();   // compiler drains vmcnt before s_barrier

        if (k0 > wrow_max) continue;   // this wave fully above diagonal

        // ---- S = Q K^T ----
        f32x4 s[2][4] = {};
#pragma unroll
        for (int kf = 0; kf < 2; kf++)
#pragma unroll
            for (int nj = 0; nj < 4; nj++) {
                short8 kfr = *(const short8*)&Ks[kf][(nj * 16 + l15) * 32 + quad * 8];
#pragma unroll
                for (int mi = 0; mi < 2; mi++)
                    s[mi][nj] = __builtin_amdgcn_mfma_f32_16x16x32_bf16(
                        qf[mi][kf], kfr, s[mi][nj], 0, 0, 0);
            }

        // ---- causal mask (only near the diagonal) ----
        if (k0 + 63 > q0 + wv * 32) {
#pragma unroll
            for (int mi = 0; mi < 2; mi++)
#pragma unroll
                for (int nj = 0; nj < 4; nj++) {
                    int key_g = k0 + nj * 16 + l15;
#pragma unroll
                    for (int r = 0; r < 4; r++) {
                        int row_g = q0 + wv * 32 + mi * 16 + quad * 4 + r;
                        if (key_g > row_g) s[mi][nj][r] = -INFINITY;
                    }
                }
        }

        // ---- online softmax + P(bf16) to LDS ----
#pragma unroll
        for (int mi = 0; mi < 2; mi++) {
#pragma unroll
            for (int r = 0; r < 4; r++) {
                float rmax = fmaxf(fmaxf(s[mi][0][r], s[mi][1][r]),
                                   fmaxf(s[mi][2][r], s[mi][3][r]));
                rmax = fmaxf(rmax, __shfl_xor(rmax, 1, 64));
                rmax = fmaxf(rmax, __shfl_xor(rmax, 2, 64));
                rmax = fmaxf(rmax, __shfl_xor(rmax, 4, 64));
                rmax = fmaxf(rmax, __shfl_xor(rmax, 8, 64));
                float mo = mrow[mi][r];
                float mn = fmaxf(mo, rmax);
                float alpha = __expf(mo - mn);
                mrow[mi][r] = mn;
                float rsum = 0.f;
#pragma unroll
                for (int nj = 0; nj < 4; nj++) {
                    float p = __expf(s[mi][nj][r] - mn);
                    s[mi][nj][r] = p;
                    rsum += p;
                }
                rsum += __shfl_xor(rsum, 1, 64);
                rsum += __shfl_xor(rsum, 2, 64);
                rsum += __shfl_xor(rsum, 4, 64);
                rsum += __shfl_xor(rsum, 8, 64);
                lrow[mi][r] = lrow[mi][r] * alpha + rsum;
#pragma unroll
                for (int nj = 0; nj < 4; nj++) acc[mi][nj][r] *= alpha;
            }
#pragma unroll
            for (int nj = 0; nj < 4; nj++) {
                int key = nj * 16 + l15;
                int kc = key >> 5, kL = key & 31;
                int rowb = (wv * 32 + mi * 16 + quad * 4) * 32 + kL;
#pragma unroll
                for (int r = 0; r < 4; r++)
                    Ps[kc][rowb + r * 32] = f2bf(s[mi][nj][r]);
            }
        }
        // same-wave LDS RAW: compiler inserts lgkmcnt wait

        // ---- O += P V ----
#pragma unroll
        for (int kc = 0; kc < 2; kc++) {
            short8 pf[2];
#pragma unroll
            for (int mi = 0; mi < 2; mi++)
                pf[mi] = *(const short8*)&Ps[kc][(wv * 32 + mi * 16 + l15) * 32 + quad * 8];
#pragma unroll
            for (int nj = 0; nj < 4; nj++) {
                short8 vf = *(const short8*)&VsT[kc][(nj * 16 + l15) * 32 + quad * 8];
#pragma unroll
                for (int mi = 0; mi < 2; mi++)
                    acc[mi][nj] = __builtin_amdgcn_mfma_f32_16x16x32_bf16(
                        pf[mi], vf, acc[mi][nj], 0, 0, 0);
            }
        }
    }

    // ---- epilogue: normalize, store bf16 (B, S, H*D_K) ----
#pragma unroll
    for (int mi = 0; mi < 2; mi++) {
        float invl[4];
#pragma unroll
        for (int r = 0; r < 4; r++) invl[r] = 1.f / lrow[mi][r];
#pragma unroll
        for (int nj = 0; nj < 4; nj++) {
            int d = nj * 16 + l15;
#pragma unroll
            for (int r = 0; r < 4; r++) {
                int row_g = q0 + wv * 32 + mi * 16 + quad * 4 + r;
                out[(size_t)(b * S_LEN + row_g) * D_MODEL + h * D_K + d] =
                    f2bf(acc[mi][nj][r] * invl[r]);
            }
        }
    }
}

// ---------------------------------------------------------------------------
extern "C" void kernel_launch(void* const* d_in, const int* in_sizes, int n_in,
                              void* d_out, int out_size, void* d_ws, size_t ws_size,
                              hipStream_t stream) {
    const float* x    = (const float*)d_in[0];
    const int*   pos  = (const int*)d_in[1];
    const float* Wqkv = (const float*)d_in[2];
    const float* Wout = (const float*)d_in[3];
    float*       out  = (float*)d_out;

    const int M = B_SZ * S_LEN;   // 4096

    // workspace (u16 elements): 58.8 MB total
    u16* qkvb = (u16*)d_ws;                            // 4096 x 3072
    u16* aob  = qkvb + (size_t)M * 3 * D_MODEL;        // 4096 x 1024
    u16* xb   = aob  + (size_t)M * D_MODEL;            // 4096 x 1024
    u16* wqb  = xb   + (size_t)M * D_MODEL;            // 3072 x 1024
    u16* wob  = wqb  + (size_t)3 * D_MODEL * D_MODEL;  // 1024 x 1024
    u16* vtb  = wob  + (size_t)D_MODEL * D_MODEL;      // B*H*D_K*S = 4096 x 1024

    // 0) casts to bf16
    cast_f32_bf16<<<(M * D_MODEL / 4 + 255) / 256, 256, 0, stream>>>(x, xb, M * D_MODEL / 4);
    cast_f32_bf16<<<(3 * D_MODEL * D_MODEL / 4 + 255) / 256, 256, 0, stream>>>(Wqkv, wqb, 3 * D_MODEL * D_MODEL / 4);
    cast_f32_bf16<<<(D_MODEL * D_MODEL / 4 + 255) / 256, 256, 0, stream>>>(Wout, wob, D_MODEL * D_MODEL / 4);

    // 1) qkv = x @ W_qkv^T
    gemm_bt_mfma<true><<<dim3(3 * D_MODEL / 128, M / 128), 256, 0, stream>>>(
        xb, wqb, qkvb, M, 3 * D_MODEL, D_MODEL);

    // 2) RoPE in place (Q scaled by 0.125)
    rope_bf16<<<(B_SZ * S_LEN * 2 * N_HEADS * 32) / 256, 256, 0, stream>>>(qkvb, pos);

    // 3) V transpose -> (B,H,D,S)
    vtrans<<<dim3(S_LEN / 64, N_HEADS, B_SZ), 256, 0, stream>>>(qkvb, vtb);

    // 4) MFMA flash attention -> aob (B,S,H*D) bf16
    attn_mfma<<<dim3(S_LEN / 128, N_HEADS, B_SZ), 256, 0, stream>>>(qkvb, vtb, aob);

    // 5) out = ao @ W_out^T (fp32 out)
    gemm_bt_mfma<false><<<dim3(D_MODEL / 128, M / 128), 256, 0, stream>>>(
        aob, wob, out, M, D_MODEL, D_MODEL);
}

// Round 5
// 249.042 us; speedup vs baseline: 16.5789x; 1.1313x over previous
//
#include <hip/hip_runtime.h>
#include <hip/hip_bf16.h>
#include <math.h>

#define D_MODEL 1024
#define N_HEADS 16
#define D_K     64
#define S_LEN   2048
#define B_SZ    2

typedef unsigned short u16;
typedef unsigned int   u32;
using short8 = __attribute__((ext_vector_type(8))) short;
using f32x4  = __attribute__((ext_vector_type(4))) float;

__device__ inline float bf2f(u16 u) { return __uint_as_float((u32)u << 16); }
__device__ inline u16 f2bf(float f) {
    __hip_bfloat16 h = __float2bfloat16(f);   // RNE
    return *(u16*)&h;
}
__device__ inline void gload_lds16(const void* g, void* l) {
    __builtin_amdgcn_global_load_lds(
        (const __attribute__((address_space(1))) unsigned int*)g,
        (__attribute__((address_space(3))) unsigned int*)l, 16, 0, 0);
}

// ---------------------------------------------------------------------------
// fp32 -> bf16 cast, float4/ushort4 vectorized.
// ---------------------------------------------------------------------------
__global__ __launch_bounds__(256)
void cast_f32_bf16(const float* __restrict__ in, u16* __restrict__ out, int n4) {
    int i = blockIdx.x * 256 + threadIdx.x;
    if (i >= n4) return;
    float4 v = ((const float4*)in)[i];
    ushort4 u;
    u.x = f2bf(v.x); u.y = f2bf(v.y); u.z = f2bf(v.z); u.w = f2bf(v.w);
    ((ushort4*)out)[i] = u;
}

// ---------------------------------------------------------------------------
// bf16 MFMA GEMM (m97 structure): C[M][N] = A[M][K] * B[N][K]^T.  (verified R2)
// ---------------------------------------------------------------------------
template <bool OUT_BF16>
__global__ __launch_bounds__(256)
void gemm_bt_mfma(const u16* __restrict__ A, const u16* __restrict__ B,
                  void* __restrict__ Cout, int M, int N, int K) {
    __shared__ u16 As[128 * 32];
    __shared__ u16 Bs[128 * 32];
    const int tid  = threadIdx.x;
    const int lane = tid & 63;
    const int wv   = tid >> 6;
    const int wm   = wv >> 1, wn = wv & 1;
    const int row0 = blockIdx.y * 128;
    const int col0 = blockIdx.x * 128;

    const int lr = lane >> 2;
    const int lc = (lane & 3) * 8;

    f32x4 acc[4][4] = {};

    for (int k0 = 0; k0 < K; k0 += 32) {
#pragma unroll
        for (int t = 0; t < 2; t++) {
            int rblk = wv * 32 + t * 16;
            gload_lds16(A + (size_t)(row0 + rblk + lr) * K + k0 + lc, &As[rblk * 32]);
            gload_lds16(B + (size_t)(col0 + rblk + lr) * K + k0 + lc, &Bs[rblk * 32]);
        }
        __syncthreads();

        short8 af[4], bfr[4];
#pragma unroll
        for (int mi = 0; mi < 4; mi++)
            af[mi] = *(const short8*)&As[(wm * 64 + mi * 16 + (lane & 15)) * 32 + (lane >> 4) * 8];
#pragma unroll
        for (int nj = 0; nj < 4; nj++)
            bfr[nj] = *(const short8*)&Bs[(wn * 64 + nj * 16 + (lane & 15)) * 32 + (lane >> 4) * 8];
#pragma unroll
        for (int mi = 0; mi < 4; mi++)
#pragma unroll
            for (int nj = 0; nj < 4; nj++)
                acc[mi][nj] = __builtin_amdgcn_mfma_f32_16x16x32_bf16(
                    af[mi], bfr[nj], acc[mi][nj], 0, 0, 0);
        __syncthreads();
    }

    const int cr = (lane >> 4) * 4;
    const int cc = lane & 15;
#pragma unroll
    for (int mi = 0; mi < 4; mi++) {
#pragma unroll
        for (int nj = 0; nj < 4; nj++) {
            int c = col0 + wn * 64 + nj * 16 + cc;
#pragma unroll
            for (int r = 0; r < 4; r++) {
                int rr = row0 + wm * 64 + mi * 16 + cr + r;
                if (OUT_BF16)
                    ((u16*)Cout)[(size_t)rr * N + c] = f2bf(acc[mi][nj][r]);
                else
                    ((float*)Cout)[(size_t)rr * N + c] = acc[mi][nj][r];
            }
        }
    }
}

// ---------------------------------------------------------------------------
// RoPE in place on bf16 qkv (Q and K slices); Q additionally scaled by
// 1/sqrt(d_k).
// ---------------------------------------------------------------------------
__global__ __launch_bounds__(256)
void rope_bf16(u16* __restrict__ qkv, const int* __restrict__ pos) {
    int idx = blockIdx.x * blockDim.x + threadIdx.x;
    int j = idx & 31;
    int h = (idx >> 5) & 15;
    int w = (idx >> 9) & 1;
    int s = (idx >> 10) & 2047;
    int b = idx >> 21;

    float p = (float)pos[s];
    float inv_freq = __powf(10000.0f, -(float)(2 * j) / 64.0f);
    float ang = p * inv_freq;
    float sn, cs;
    sincosf(ang, &sn, &cs);
    float sc = (w == 0) ? 0.125f : 1.0f;

    size_t base = (((size_t)(b * S_LEN + s) * 3 + w) * D_MODEL) + h * D_K + 2 * j;
    float x1 = bf2f(qkv[base]);
    float x2 = bf2f(qkv[base + 1]);
    qkv[base]     = f2bf((x1 * cs - x2 * sn) * sc);
    qkv[base + 1] = f2bf((x1 * sn + x2 * cs) * sc);
}

// ---------------------------------------------------------------------------
// V transpose: qkv V slice (B,S,3,H,D) -> VT (B,H,D,S). 64x64 LDS tile.
// ---------------------------------------------------------------------------
__global__ __launch_bounds__(256)
void vtrans(const u16* __restrict__ qkv, u16* __restrict__ VT) {
    __shared__ u16 t[64][68];
    const int st = blockIdx.x, h = blockIdx.y, b = blockIdx.z;
    const int tid = threadIdx.x;
    const int bh = b * N_HEADS + h;

#pragma unroll
    for (int i = 0; i < 4; i++) {
        int e  = tid + i * 256;
        int sl = e >> 4;
        int c4 = e & 15;
        ushort4 v = *(const ushort4*)&qkv[((size_t)(b * S_LEN + st * 64 + sl) * 3 + 2) * D_MODEL
                                          + h * D_K + c4 * 4];
        *(ushort4*)&t[sl][c4 * 4] = v;
    }
    __syncthreads();
#pragma unroll
    for (int i = 0; i < 4; i++) {
        int e  = tid + i * 256;
        int d  = e >> 4;
        int s4 = e & 15;
        ushort4 o;
        o.x = t[s4 * 4 + 0][d];
        o.y = t[s4 * 4 + 1][d];
        o.z = t[s4 * 4 + 2][d];
        o.w = t[s4 * 4 + 3][d];
        *(ushort4*)&VT[((size_t)bh * D_K + d) * S_LEN + st * 64 + s4 * 4] = o;
    }
}

// ---------------------------------------------------------------------------
// MFMA flash attention v2 (causal), S^T formulation.
// Block = 4 waves per (b, h, 64-query tile); wave w owns queries w*16..+15.
// S^T = K·Q^T (A=K, B=Q) -> C-layout: row=key=quad*4+r, col=query=l15:
//   one query per lane -> softmax reductions are 15 in-lane fmax + 2 shfl_xor.
// P: lane holds 4 consecutive keys per 16-key tile -> packed bf16-pair b64
// stores into a wave-private [query][key] LDS strip (row stride 68 u16),
// no barrier, bank-floor traffic. PV: A=P (m=query), B=VsT (n=d) -> O in
// standard C-layout. alpha/invl cross lanes via 4-lane broadcasts.
// ---------------------------------------------------------------------------
__global__ __launch_bounds__(256)
void attn_mfma(const u16* __restrict__ qkv, const u16* __restrict__ VT,
               u16* __restrict__ out) {
    __shared__ u16 Ks[2][64 * 32];    // [kf d-chunk][key*32 + dL]
    __shared__ u16 VsT[2][64 * 32];   // [kc key-chunk][d*32 + kL]
    __shared__ u16 Ps[4][16 * 68];    // per-wave [query 16][key 64 + pad 4]

    const int tid  = threadIdx.x;
    const int lane = tid & 63;
    const int wv   = tid >> 6;
    const int qt   = gridDim.x - 1 - blockIdx.x;   // longest blocks first
    const int h    = blockIdx.y, b = blockIdx.z;
    const int bh   = b * N_HEADS + h;
    const int q0   = qt * 64;
    const int qw0  = q0 + wv * 16;                 // this wave's first query
    const int l15  = lane & 15;
    const int quad = lane >> 4;

    const size_t vtb = (size_t)bh * D_K * S_LEN;
    u16* Psw = &Ps[wv][0];

    // Q fragments (B-operand layout [n=query l15][k=d quad*8+j]); Q pre-scaled.
    short8 qf[2];
#pragma unroll
    for (int kf = 0; kf < 2; kf++)
        qf[kf] = *(const short8*)&qkv[((size_t)(b * S_LEN + qw0 + l15) * 3 + 0) * D_MODEL
                                      + h * D_K + kf * 32 + quad * 8];

    f32x4 acc[4] = {};          // O: row=query quad*4+r, col=d nj*16+l15
    float mq = -INFINITY;       // per-lane stats for query l15 (replicated per quad)
    float lq = 0.f;

    for (int kt = 0; kt <= qt; kt++) {
        const int k0 = kt * 64;
        __syncthreads();   // prior iter's Ks/VsT reads complete
        {
            const int lr = lane >> 2;
            const int lc = (lane & 3) * 8;
#pragma unroll
            for (int kf = 0; kf < 2; kf++)
                gload_lds16(qkv + ((size_t)(b * S_LEN + k0 + wv * 16 + lr) * 3 + 1) * D_MODEL
                                + h * D_K + kf * 32 + lc,
                            &Ks[kf][(wv * 16) * 32]);
#pragma unroll
            for (int kc = 0; kc < 2; kc++)
                gload_lds16(VT + vtb + (size_t)(wv * 16 + lr) * S_LEN + k0 + kc * 32 + lc,
                            &VsT[kc][(wv * 16) * 32]);
        }
        __syncthreads();   // drains vmcnt -> tiles complete

        if (k0 > qw0 + 15) continue;   // wave fully above diagonal

        // ---- S^T = K·Q^T : s[nj] rows=keys nj*16+quad*4+r, col=query l15 ----
        f32x4 s[4] = {};
#pragma unroll
        for (int kf = 0; kf < 2; kf++)
#pragma unroll
            for (int nj = 0; nj < 4; nj++) {
                short8 kfr = *(const short8*)&Ks[kf][(nj * 16 + l15) * 32 + quad * 8];
                s[nj] = __builtin_amdgcn_mfma_f32_16x16x32_bf16(kfr, qf[kf], s[nj], 0, 0, 0);
            }

        // ---- causal mask (diagonal tile only) ----
        if (k0 + 63 > qw0) {
            const int row_g = qw0 + l15;
#pragma unroll
            for (int nj = 0; nj < 4; nj++)
#pragma unroll
                for (int r = 0; r < 4; r++) {
                    int key_g = k0 + nj * 16 + quad * 4 + r;
                    if (key_g > row_g) s[nj][r] = -INFINITY;
                }
        }

        // ---- online softmax: one query per lane, 16 keys in-lane ----
        float rmax = s[0][0];
#pragma unroll
        for (int nj = 0; nj < 4; nj++)
#pragma unroll
            for (int r = 0; r < 4; r++) rmax = fmaxf(rmax, s[nj][r]);
        rmax = fmaxf(rmax, __shfl_xor(rmax, 16, 64));
        rmax = fmaxf(rmax, __shfl_xor(rmax, 32, 64));
        float mn = fmaxf(mq, rmax);
        float alpha = __expf(mq - mn);
        mq = mn;
        float rsum = 0.f;
#pragma unroll
        for (int nj = 0; nj < 4; nj++)
#pragma unroll
            for (int r = 0; r < 4; r++) {
                float p = __expf(s[nj][r] - mn);
                s[nj][r] = p;
                rsum += p;
            }
        rsum += __shfl_xor(rsum, 16, 64);
        rsum += __shfl_xor(rsum, 32, 64);
        lq = lq * alpha + rsum;

        // ---- rescale O: alpha lives at lane l15=query; O rows are quad*4+r ----
#pragma unroll
        for (int r = 0; r < 4; r++) {
            float ar = __shfl(alpha, quad * 4 + r, 64);
#pragma unroll
            for (int nj = 0; nj < 4; nj++) acc[nj][r] *= ar;
        }

        // ---- P (bf16 pairs) -> wave-private LDS strip [query][key] ----
#pragma unroll
        for (int nj = 0; nj < 4; nj++) {
            u32 lo = ((u32)f2bf(s[nj][1]) << 16) | f2bf(s[nj][0]);
            u32 hi = ((u32)f2bf(s[nj][3]) << 16) | f2bf(s[nj][2]);
            uint2 pk; pk.x = lo; pk.y = hi;
            *(uint2*)&Psw[l15 * 68 + nj * 16 + quad * 4] = pk;
        }
        // same-wave LDS RAW -> compiler inserts lgkmcnt wait

        // ---- O += P·V : A=P[m=query][k=key], B=VsT[n=d][k=key] ----
#pragma unroll
        for (int kf = 0; kf < 2; kf++) {
            const u16* pp = &Psw[l15 * 68 + kf * 32 + quad * 8];
            uint2 plo = *(const uint2*)pp;
            uint2 phi = *(const uint2*)(pp + 4);
            u32 praw[4] = { plo.x, plo.y, phi.x, phi.y };
            short8 pf = *(const short8*)praw;
#pragma unroll
            for (int nj = 0; nj < 4; nj++) {
                short8 vf = *(const short8*)&VsT[kf][(nj * 16 + l15) * 32 + quad * 8];
                acc[nj] = __builtin_amdgcn_mfma_f32_16x16x32_bf16(pf, vf, acc[nj], 0, 0, 0);
            }
        }
    }

    // ---- epilogue: normalize (invl per query), store bf16 (B,S,H*D) ----
    float invl = 1.f / lq;
#pragma unroll
    for (int r = 0; r < 4; r++) {
        float ir = __shfl(invl, quad * 4 + r, 64);
        int row_g = qw0 + quad * 4 + r;
#pragma unroll
        for (int nj = 0; nj < 4; nj++)
            out[(size_t)(b * S_LEN + row_g) * D_MODEL + h * D_K + nj * 16 + l15] =
                f2bf(acc[nj][r] * ir);
    }
}

// ---------------------------------------------------------------------------
extern "C" void kernel_launch(void* const* d_in, const int* in_sizes, int n_in,
                              void* d_out, int out_size, void* d_ws, size_t ws_size,
                              hipStream_t stream) {
    const float* x    = (const float*)d_in[0];
    const int*   pos  = (const int*)d_in[1];
    const float* Wqkv = (const float*)d_in[2];
    const float* Wout = (const float*)d_in[3];
    float*       out  = (float*)d_out;

    const int M = B_SZ * S_LEN;   // 4096

    u16* qkvb = (u16*)d_ws;                            // 4096 x 3072
    u16* aob  = qkvb + (size_t)M * 3 * D_MODEL;        // 4096 x 1024
    u16* xb   = aob  + (size_t)M * D_MODEL;            // 4096 x 1024
    u16* wqb  = xb   + (size_t)M * D_MODEL;            // 3072 x 1024
    u16* wob  = wqb  + (size_t)3 * D_MODEL * D_MODEL;  // 1024 x 1024
    u16* vtb  = wob  + (size_t)D_MODEL * D_MODEL;      // 4096 x 1024

    cast_f32_bf16<<<(M * D_MODEL / 4 + 255) / 256, 256, 0, stream>>>(x, xb, M * D_MODEL / 4);
    cast_f32_bf16<<<(3 * D_MODEL * D_MODEL / 4 + 255) / 256, 256, 0, stream>>>(Wqkv, wqb, 3 * D_MODEL * D_MODEL / 4);
    cast_f32_bf16<<<(D_MODEL * D_MODEL / 4 + 255) / 256, 256, 0, stream>>>(Wout, wob, D_MODEL * D_MODEL / 4);

    gemm_bt_mfma<true><<<dim3(3 * D_MODEL / 128, M / 128), 256, 0, stream>>>(
        xb, wqb, qkvb, M, 3 * D_MODEL, D_MODEL);

    rope_bf16<<<(B_SZ * S_LEN * 2 * N_HEADS * 32) / 256, 256, 0, stream>>>(qkvb, pos);

    vtrans<<<dim3(S_LEN / 64, N_HEADS, B_SZ), 256, 0, stream>>>(qkvb, vtb);

    attn_mfma<<<dim3(S_LEN / 64, N_HEADS, B_SZ), 256, 0, stream>>>(qkvb, vtb, aob);

    gemm_bt_mfma<false><<<dim3(D_MODEL / 128, M / 128), 256, 0, stream>>>(
        aob, wob, out, M, D_MODEL, D_MODEL);
}